// Round 1
// baseline (4981.690 us; speedup 1.0000x reference)
//
#include <hip/hip_runtime.h>

// Problem constants (B,T,C,F fixed by harness)
constexpr int BB = 8;
constexpr int TT = 512;
constexpr int CHN = 8;
constexpr int FF = 257;
constexpr int TAPS = 5;
constexpr int DELAY = 3;
constexpr int NBF = BB * FF;          // 2056 independent (b,f) systems
constexpr int ROWQ = 20;              // LDS floats per t-row (8ch*2 = 16 + pad to 20: 16B-aligned, bank-spread)
constexpr int ROWS_LDS = 136;         // 128-chunk + 7 halo + 1
constexpr int MC = 48;                // augmented matrix cols (40 R + 8 rhs)
constexpr int RS = 98;                // solver LDS row stride in floats (48*2 + 2 pad)

// ---------------------------------------------------------------------------
// K1: (B,T,C,F) re/im -> Yg[b][f][t][c][2]  (time-contiguous complex layout)
// ---------------------------------------------------------------------------
__global__ void k_pack(const float* __restrict__ re, const float* __restrict__ im,
                       float* __restrict__ Yg) {
  const int ft = blockIdx.x, tt = blockIdx.y, b = blockIdx.z;
  const int f0 = ft * 32, t0 = tt * 16;
  __shared__ float ls[32 * 258];
  const int tid = threadIdx.x;
  const int l = tid & 31;   // f lane
  const int r = tid >> 5;   // 0..7
  const int f = f0 + l;
  if (f < FF) {
    for (int k = 0; k < 32; ++k) {
      const int task = r + 8 * k;       // 0..255 -> (t,c,ri)
      const int ri = task & 1;
      const int c  = (task >> 1) & 7;
      const int t  = task >> 4;         // 0..15
      const float* src = ri ? im : re;
      const float v = src[(((size_t)b * TT + t0 + t) * CHN + c) * FF + f];
      ls[l * 258 + (t * 16 + c * 2 + ri)] = v;
    }
  }
  __syncthreads();
  for (int ff = 0; ff < 32; ++ff) {
    const int fg = f0 + ff;
    if (fg >= FF) break;
    Yg[(((size_t)b * FF + fg) * TT + t0) * 16 + tid] = ls[ff * 258 + tid];
  }
}

// ---------------------------------------------------------------------------
// K2: initial power[b][f][t] = mean_c |Y|^2
// ---------------------------------------------------------------------------
__global__ void k_power0(const float* __restrict__ Yg, float* __restrict__ pw) {
  const size_t idx = (size_t)blockIdx.x * blockDim.x + threadIdx.x;
  if (idx >= (size_t)NBF * TT) return;
  const float4* y4 = (const float4*)(Yg + idx * 16);
  float s = 0.f;
#pragma unroll
  for (int k = 0; k < 4; ++k) {
    float4 v = y4[k];
    s += v.x * v.x + v.y * v.y + v.z * v.z + v.w * v.w;
  }
  pw[idx] = s * (1.0f / CHN);
}

// ---------------------------------------------------------------------------
// K3: per (b,f) accumulate M = [R | b] (40x48 complex).
//   M[i=(p,d)][j] = sum_{t>=7} w[t] * conj(Y[d,t-3-p]) * z_j[t]
//   z_j = Y[e,t-3-q] for j=(q,e)<40, z_j = Y[e,t] for j=40+e.
// One wave per (b,f); 60 active lanes each own an 8x4 complex tile.
// ---------------------------------------------------------------------------
__global__ __launch_bounds__(64) void k_corr(const float* __restrict__ Yg,
                                             const float* __restrict__ pw,
                                             float2* __restrict__ Mg) {
  const int bf = blockIdx.x;
  __shared__ float yl[ROWS_LDS * ROWQ];
  __shared__ float wl[TT];
  const int lane = threadIdx.x;
  for (int t = lane; t < TT; t += 64) {
    const float p = pw[(size_t)bf * TT + t];
    wl[t] = (t >= DELAY + TAPS - 1) ? (1.0f / fmaxf(p, 1e-10f)) : 0.0f;
  }
  const bool active = lane < 60;
  const int it = lane / 12;                 // 0..4  (p of x-block)
  const int jt = lane - it * 12;            // 0..11 (4-col z-block)
  const int xoff = DELAY + it;              // x row = t - xoff
  const int zoff = (jt < 10) ? (DELAY + (jt >> 1)) : 0;
  const int ze0  = (jt < 10) ? ((jt & 1) * 4) : ((jt - 10) * 4);

  float accr[8][4], acci[8][4];
#pragma unroll
  for (int l = 0; l < 8; ++l)
#pragma unroll
    for (int m = 0; m < 4; ++m) { accr[l][m] = 0.f; acci[l][m] = 0.f; }

  const float4* ybase4 = (const float4*)(Yg + (size_t)bf * TT * 16);
  for (int ck = 0; ck < 4; ++ck) {
    const int Lc = (ck == 0) ? (DELAY + TAPS - 1) : ck * 128;
    const int Uc = (ck + 1) * 128;
    const int r0 = Lc - 7;                  // ck0 -> 0
    __syncthreads();
    const int nf4 = (Uc - r0) * 4;
    for (int fi = lane; fi < nf4; fi += 64) {
      const int row = fi >> 2, wq = fi & 3;
      float4 v = ybase4[(size_t)(r0 + row) * 4 + wq];
      *((float4*)&yl[row * ROWQ + wq * 4]) = v;
    }
    __syncthreads();
    if (active) {
      const float* xrow = &yl[(Lc - xoff - r0) * ROWQ];
      const float* zrow = &yl[(Lc - zoff - r0) * ROWQ + ze0 * 2];
      for (int t = Lc; t < Uc; ++t) {
        const float w = wl[t];
        float xv[16], zv[8];
        *(float4*)&xv[0]  = *(const float4*)(xrow + 0);
        *(float4*)&xv[4]  = *(const float4*)(xrow + 4);
        *(float4*)&xv[8]  = *(const float4*)(xrow + 8);
        *(float4*)&xv[12] = *(const float4*)(xrow + 12);
        *(float4*)&zv[0]  = *(const float4*)(zrow + 0);
        *(float4*)&zv[4]  = *(const float4*)(zrow + 4);
#pragma unroll
        for (int l = 0; l < 8; ++l) {
          const float ar = w * xv[2 * l];
          const float br = w * xv[2 * l + 1];
#pragma unroll
          for (int m = 0; m < 4; ++m) {
            accr[l][m] += ar * zv[2 * m]     + br * zv[2 * m + 1];
            acci[l][m] += ar * zv[2 * m + 1] - br * zv[2 * m];
          }
        }
        xrow += ROWQ; zrow += ROWQ;
      }
    }
  }
  if (active) {
#pragma unroll
    for (int l = 0; l < 8; ++l) {
      const int i = it * 8 + l;
#pragma unroll
      for (int m = 0; m < 4; ++m) {
        const int j = jt * 4 + m;
        float rr = accr[l][m];
        if (i == j) rr += 1e-10f;           // + eps * I on the R diagonal
        Mg[((size_t)bf * 40 + i) * MC + j] = make_float2(rr, acci[l][m]);
      }
    }
  }
}

// ---------------------------------------------------------------------------
// K4: per (b,f) solve (R+eps I) G = b via unpivoted elimination (R is HPD).
// One wave per system, in LDS.
// ---------------------------------------------------------------------------
__global__ __launch_bounds__(64) void k_solve(const float2* __restrict__ Mg,
                                              float2* __restrict__ Gg) {
  const int bf = blockIdx.x;
  __shared__ float ml[40 * RS];
  const int lane = threadIdx.x;
  for (int idx = lane; idx < 40 * MC; idx += 64) {
    const int i = idx / MC, j = idx - i * MC;
    float2 v = Mg[((size_t)bf * 40 + i) * MC + j];
    *(float2*)&ml[i * RS + j * 2] = v;
  }
  __syncthreads();
  const int li = lane >> 3, lj = lane & 7;
  // forward elimination
  for (int k = 0; k < 40; ++k) {
    const float2 pv = *(float2*)&ml[k * RS + k * 2];
    const float den = pv.x * pv.x + pv.y * pv.y;
    const float inr = pv.x / den, ini = -pv.y / den;
    for (int i = k + 1 + li; i < 40; i += 8) {
      const float2 aik = *(float2*)&ml[i * RS + k * 2];
      const float fr = aik.x * inr - aik.y * ini;
      const float fi = aik.x * ini + aik.y * inr;
      for (int j = k + 1 + lj; j < MC; j += 8) {
        const float2 ak = *(float2*)&ml[k * RS + j * 2];
        float2 ai = *(float2*)&ml[i * RS + j * 2];
        ai.x -= fr * ak.x - fi * ak.y;
        ai.y -= fr * ak.y + fi * ak.x;
        *(float2*)&ml[i * RS + j * 2] = ai;
      }
    }
    __syncthreads();
  }
  // back substitution: lanes (cc = lane>>3 partial-chunks) x (e = lane&7 rhs)
  const int e = lane & 7, cc = lane >> 3;
  for (int k = 39; k >= 0; --k) {
    float sr = 0.f, si = 0.f;
    for (int j = k + 1 + cc; j < 40; j += 8) {
      const float2 u = *(float2*)&ml[k * RS + j * 2];
      const float2 x = *(float2*)&ml[j * RS + (40 + e) * 2];
      sr += u.x * x.x - u.y * x.y;
      si += u.x * x.y + u.y * x.x;
    }
    sr += __shfl_xor(sr, 8);  si += __shfl_xor(si, 8);
    sr += __shfl_xor(sr, 16); si += __shfl_xor(si, 16);
    sr += __shfl_xor(sr, 32); si += __shfl_xor(si, 32);
    if (cc == 0) {
      const float2 pvt = *(float2*)&ml[k * RS + k * 2];
      const float den = pvt.x * pvt.x + pvt.y * pvt.y;
      const float inr = pvt.x / den, ini = -pvt.y / den;
      const float2 rhs = *(float2*)&ml[k * RS + (40 + e) * 2];
      const float nr = rhs.x - sr, ni = rhs.y - si;
      *(float2*)&ml[k * RS + (40 + e) * 2] =
          make_float2(nr * inr - ni * ini, nr * ini + ni * inr);
    }
    __syncthreads();
  }
  for (int idx = lane; idx < 320; idx += 64) {
    const int i = idx >> 3, ee = idx & 7;
    Gg[(size_t)bf * 320 + idx] = *(float2*)&ml[i * RS + (40 + ee) * 2];
  }
}

// ---------------------------------------------------------------------------
// K5: E[e,t] = Y[e,t] - sum_{p,d} G[p,d,e] * Y[d,t-3-p]
// MODE 0: write power = mean_e |E|^2 (for iteration 2), discard E.
// MODE 1: overwrite Yg with E in place (reverse chunk order makes this safe:
//         halo reads only touch rows strictly below the written range).
// ---------------------------------------------------------------------------
template <int MODE>
__global__ __launch_bounds__(64) void k_tail(float* __restrict__ Yg,
                                             const float2* __restrict__ Gg,
                                             float* __restrict__ pw) {
  const int bf = blockIdx.x;
  __shared__ float yl[ROWS_LDS * ROWQ];
  __shared__ float gl[640];
  const int lane = threadIdx.x;
  for (int idx = lane; idx < 320; idx += 64) {
    float2 g = Gg[(size_t)bf * 320 + idx];
    *(float2*)&gl[idx * 2] = g;
  }
  float* ybase = Yg + (size_t)bf * TT * 16;
  for (int ck = 3; ck >= 0; --ck) {
    const int Lc = ck * 128, Uc = Lc + 128;
    const int r0 = (ck == 0) ? 0 : (Lc - 7);
    __syncthreads();
    const int nf4 = (Uc - r0) * 4;
    for (int fi = lane; fi < nf4; fi += 64) {
      const int row = fi >> 2, wq = fi & 3;
      float4 v = *((const float4*)ybase + (size_t)(r0 + row) * 4 + wq);
      *((float4*)&yl[row * ROWQ + wq * 4]) = v;
    }
    __syncthreads();
    float acc[2][16];
#pragma unroll
    for (int s = 0; s < 2; ++s) {
      const int t = Lc + lane + s * 64;
      const float* yr = &yl[(t - r0) * ROWQ];
#pragma unroll
      for (int q = 0; q < 16; ++q) acc[s][q] = yr[q];
    }
#pragma unroll
    for (int p = 0; p < TAPS; ++p) {
#pragma unroll
      for (int d = 0; d < CHN; ++d) {
        const float* gp = &gl[((p * 8 + d) * 8) * 2];
        float gre[8], gim[8];
#pragma unroll
        for (int ee = 0; ee < 8; ++ee) { gre[ee] = gp[2 * ee]; gim[ee] = gp[2 * ee + 1]; }
#pragma unroll
        for (int s = 0; s < 2; ++s) {
          const int t = Lc + lane + s * 64;
          const int rp = t - DELAY - p;
          if (rp >= 0) {
            const float yrv = yl[(rp - r0) * ROWQ + d * 2];
            const float yiv = yl[(rp - r0) * ROWQ + d * 2 + 1];
#pragma unroll
            for (int ee = 0; ee < 8; ++ee) {
              acc[s][2 * ee]     -= gre[ee] * yrv - gim[ee] * yiv;
              acc[s][2 * ee + 1] -= gre[ee] * yiv + gim[ee] * yrv;
            }
          }
        }
      }
    }
    if (MODE == 0) {
#pragma unroll
      for (int s = 0; s < 2; ++s) {
        const int t = Lc + lane + s * 64;
        float ss = 0.f;
#pragma unroll
        for (int q = 0; q < 16; ++q) ss += acc[s][q] * acc[s][q];
        pw[(size_t)bf * TT + t] = ss * (1.0f / CHN);
      }
    } else {
#pragma unroll
      for (int s = 0; s < 2; ++s) {
        const int t = Lc + lane + s * 64;
        float4* dst = (float4*)(ybase + (size_t)t * 16);
        dst[0] = make_float4(acc[s][0], acc[s][1], acc[s][2], acc[s][3]);
        dst[1] = make_float4(acc[s][4], acc[s][5], acc[s][6], acc[s][7]);
        dst[2] = make_float4(acc[s][8], acc[s][9], acc[s][10], acc[s][11]);
        dst[3] = make_float4(acc[s][12], acc[s][13], acc[s][14], acc[s][15]);
      }
    }
  }
}

// ---------------------------------------------------------------------------
// K6: Yg[b][f][t][c][2] -> out[b][t][c][f][2]
// ---------------------------------------------------------------------------
__global__ void k_unpack(const float* __restrict__ Yg, float* __restrict__ out) {
  const int ft = blockIdx.x, tt = blockIdx.y, b = blockIdx.z;
  const int f0 = ft * 32, t0 = tt * 16;
  __shared__ float ls[32 * 258];
  const int tid = threadIdx.x;
  for (int ff = 0; ff < 32; ++ff) {
    const int fg = f0 + ff;
    if (fg >= FF) break;
    ls[ff * 258 + tid] = Yg[(((size_t)b * FF + fg) * TT + t0) * 16 + tid];
  }
  __syncthreads();
  const int l = tid & 31, r = tid >> 5;
  const int fg = f0 + l;
  if (fg < FF) {
    for (int k = 0; k < 16; ++k) {
      const int task = r + 8 * k;          // 0..127 -> (t,c)
      const int t = task >> 3, c = task & 7;
      const float2 v = *(float2*)&ls[l * 258 + t * 16 + c * 2];
      *(float2*)&out[((((size_t)b * TT + t0 + t) * CHN + c) * FF + fg) * 2] = v;
    }
  }
}

// ---------------------------------------------------------------------------
extern "C" void kernel_launch(void* const* d_in, const int* in_sizes, int n_in,
                              void* d_out, int out_size, void* d_ws, size_t ws_size,
                              hipStream_t stream) {
  const float* re = (const float*)d_in[0];
  const float* im = (const float*)d_in[1];
  float* ws = (float*)d_ws;

  float*  Yg = ws;                                        // NBF*T*16 floats  (67.4 MB)
  float*  pw = Yg + (size_t)NBF * TT * 16;                // NBF*T            (4.2 MB)
  float2* Mg = (float2*)(pw + (size_t)NBF * TT);          // NBF*40*48 cplx   (31.6 MB)
  float2* Gg = Mg + (size_t)NBF * 40 * MC;                // NBF*320 cplx     (5.3 MB)
  float*  out = (float*)d_out;

  const dim3 gridT(9, 32, BB);
  k_pack<<<gridT, 256, 0, stream>>>(re, im, Yg);

  {
    const int n = NBF * TT;
    k_power0<<<(n + 255) / 256, 256, 0, stream>>>(Yg, pw);
  }

  for (int iter = 0; iter < 2; ++iter) {
    k_corr<<<NBF, 64, 0, stream>>>(Yg, pw, Mg);
    k_solve<<<NBF, 64, 0, stream>>>(Mg, Gg);
    if (iter == 0)
      k_tail<0><<<NBF, 64, 0, stream>>>(Yg, Gg, pw);   // -> power for iter 2
    else
      k_tail<1><<<NBF, 64, 0, stream>>>(Yg, Gg, pw);   // -> E in place
  }

  k_unpack<<<gridT, 256, 0, stream>>>(Yg, out);
}

// Round 2
// 1481.210 us; speedup vs baseline: 3.3633x; 3.3633x over previous
//
#include <hip/hip_runtime.h>

// Problem constants (B,T,C,F fixed by harness)
constexpr int BB = 8;
constexpr int TT = 512;
constexpr int CHN = 8;
constexpr int FF = 257;
constexpr int TAPS = 5;
constexpr int DELAY = 3;
constexpr int NBF = BB * FF;          // 2056 independent (b,f) systems
constexpr int ROWQ = 20;              // LDS floats per t-row (8ch*2 = 16 + pad to 20)
constexpr int ROWS_LDS = 136;         // k_corr: 128-chunk + 7 halo + 1
constexpr int MC = 48;                // augmented matrix cols (40 R + 8 rhs)
constexpr int RS = 98;                // solver LDS row stride in floats (48*2 + 2 pad)

// ---------------------------------------------------------------------------
// K1: (B,T,C,F) re/im -> Yg[b][f][t][c][2]  (time-contiguous complex layout)
// ---------------------------------------------------------------------------
__global__ void k_pack(const float* __restrict__ re, const float* __restrict__ im,
                       float* __restrict__ Yg) {
  const int ft = blockIdx.x, tt = blockIdx.y, b = blockIdx.z;
  const int f0 = ft * 32, t0 = tt * 16;
  __shared__ float ls[32 * 258];
  const int tid = threadIdx.x;
  const int l = tid & 31;   // f lane
  const int r = tid >> 5;   // 0..7
  const int f = f0 + l;
  if (f < FF) {
    for (int k = 0; k < 32; ++k) {
      const int task = r + 8 * k;       // 0..255 -> (t,c,ri)
      const int ri = task & 1;
      const int c  = (task >> 1) & 7;
      const int t  = task >> 4;         // 0..15
      const float* src = ri ? im : re;
      const float v = src[(((size_t)b * TT + t0 + t) * CHN + c) * FF + f];
      ls[l * 258 + (t * 16 + c * 2 + ri)] = v;
    }
  }
  __syncthreads();
  for (int ff = 0; ff < 32; ++ff) {
    const int fg = f0 + ff;
    if (fg >= FF) break;
    Yg[(((size_t)b * FF + fg) * TT + t0) * 16 + tid] = ls[ff * 258 + tid];
  }
}

// ---------------------------------------------------------------------------
// K2: initial power[b][f][t] = mean_c |Y|^2
// ---------------------------------------------------------------------------
__global__ void k_power0(const float* __restrict__ Yg, float* __restrict__ pw) {
  const size_t idx = (size_t)blockIdx.x * blockDim.x + threadIdx.x;
  if (idx >= (size_t)NBF * TT) return;
  const float4* y4 = (const float4*)(Yg + idx * 16);
  float s = 0.f;
#pragma unroll
  for (int k = 0; k < 4; ++k) {
    float4 v = y4[k];
    s += v.x * v.x + v.y * v.y + v.z * v.z + v.w * v.w;
  }
  pw[idx] = s * (1.0f / CHN);
}

// ---------------------------------------------------------------------------
// K3: per (b,f) accumulate M = [R | b] (40x48 complex).
//   M[i=(p,d)][j] = sum_{t>=7} w[t] * conj(Y[d,t-3-p]) * z_j[t]
//   z_j = Y[e,t-3-q] for j=(q,e)<40, z_j = Y[e,t] for j=40+e.
// One wave per (b,f); 60 active lanes each own an 8x4 complex tile.
// ---------------------------------------------------------------------------
__global__ __launch_bounds__(64) void k_corr(const float* __restrict__ Yg,
                                             const float* __restrict__ pw,
                                             float2* __restrict__ Mg) {
  const int bf = blockIdx.x;
  __shared__ float yl[ROWS_LDS * ROWQ];
  __shared__ float wl[TT];
  const int lane = threadIdx.x;
  for (int t = lane; t < TT; t += 64) {
    const float p = pw[(size_t)bf * TT + t];
    wl[t] = (t >= DELAY + TAPS - 1) ? (1.0f / fmaxf(p, 1e-10f)) : 0.0f;
  }
  const bool active = lane < 60;
  const int it = lane / 12;                 // 0..4  (p of x-block)
  const int jt = lane - it * 12;            // 0..11 (4-col z-block)
  const int xoff = DELAY + it;              // x row = t - xoff
  const int zoff = (jt < 10) ? (DELAY + (jt >> 1)) : 0;
  const int ze0  = (jt < 10) ? ((jt & 1) * 4) : ((jt - 10) * 4);

  float accr[8][4], acci[8][4];
#pragma unroll
  for (int l = 0; l < 8; ++l)
#pragma unroll
    for (int m = 0; m < 4; ++m) { accr[l][m] = 0.f; acci[l][m] = 0.f; }

  const float4* ybase4 = (const float4*)(Yg + (size_t)bf * TT * 16);
  for (int ck = 0; ck < 4; ++ck) {
    const int Lc = (ck == 0) ? (DELAY + TAPS - 1) : ck * 128;
    const int Uc = (ck + 1) * 128;
    const int r0 = Lc - 7;                  // ck0 -> 0
    __syncthreads();
    const int nf4 = (Uc - r0) * 4;
    for (int fi = lane; fi < nf4; fi += 64) {
      const int row = fi >> 2, wq = fi & 3;
      float4 v = ybase4[(size_t)(r0 + row) * 4 + wq];
      *((float4*)&yl[row * ROWQ + wq * 4]) = v;
    }
    __syncthreads();
    if (active) {
      const float* xrow = &yl[(Lc - xoff - r0) * ROWQ];
      const float* zrow = &yl[(Lc - zoff - r0) * ROWQ + ze0 * 2];
      for (int t = Lc; t < Uc; ++t) {
        const float w = wl[t];
        float xv[16], zv[8];
        *(float4*)&xv[0]  = *(const float4*)(xrow + 0);
        *(float4*)&xv[4]  = *(const float4*)(xrow + 4);
        *(float4*)&xv[8]  = *(const float4*)(xrow + 8);
        *(float4*)&xv[12] = *(const float4*)(xrow + 12);
        *(float4*)&zv[0]  = *(const float4*)(zrow + 0);
        *(float4*)&zv[4]  = *(const float4*)(zrow + 4);
#pragma unroll
        for (int l = 0; l < 8; ++l) {
          const float ar = w * xv[2 * l];
          const float br = w * xv[2 * l + 1];
#pragma unroll
          for (int m = 0; m < 4; ++m) {
            accr[l][m] += ar * zv[2 * m]     + br * zv[2 * m + 1];
            acci[l][m] += ar * zv[2 * m + 1] - br * zv[2 * m];
          }
        }
        xrow += ROWQ; zrow += ROWQ;
      }
    }
  }
  if (active) {
#pragma unroll
    for (int l = 0; l < 8; ++l) {
      const int i = it * 8 + l;
#pragma unroll
      for (int m = 0; m < 4; ++m) {
        const int j = jt * 4 + m;
        float rr = accr[l][m];
        if (i == j) rr += 1e-10f;           // + eps * I on the R diagonal
        Mg[((size_t)bf * 40 + i) * MC + j] = make_float2(rr, acci[l][m]);
      }
    }
  }
}

// ---------------------------------------------------------------------------
// K4: per (b,f) solve (R+eps I) G = b via unpivoted elimination (R is HPD).
// One wave per system, in LDS.
// ---------------------------------------------------------------------------
__global__ __launch_bounds__(64) void k_solve(const float2* __restrict__ Mg,
                                              float2* __restrict__ Gg) {
  const int bf = blockIdx.x;
  __shared__ float ml[40 * RS];
  const int lane = threadIdx.x;
  for (int idx = lane; idx < 40 * MC; idx += 64) {
    const int i = idx / MC, j = idx - i * MC;
    float2 v = Mg[((size_t)bf * 40 + i) * MC + j];
    *(float2*)&ml[i * RS + j * 2] = v;
  }
  __syncthreads();
  const int li = lane >> 3, lj = lane & 7;
  // forward elimination
  for (int k = 0; k < 40; ++k) {
    const float2 pv = *(float2*)&ml[k * RS + k * 2];
    const float den = pv.x * pv.x + pv.y * pv.y;
    const float inr = pv.x / den, ini = -pv.y / den;
    for (int i = k + 1 + li; i < 40; i += 8) {
      const float2 aik = *(float2*)&ml[i * RS + k * 2];
      const float fr = aik.x * inr - aik.y * ini;
      const float fi = aik.x * ini + aik.y * inr;
      for (int j = k + 1 + lj; j < MC; j += 8) {
        const float2 ak = *(float2*)&ml[k * RS + j * 2];
        float2 ai = *(float2*)&ml[i * RS + j * 2];
        ai.x -= fr * ak.x - fi * ak.y;
        ai.y -= fr * ak.y + fi * ak.x;
        *(float2*)&ml[i * RS + j * 2] = ai;
      }
    }
    __syncthreads();
  }
  // back substitution: lanes (cc = lane>>3 partial-chunks) x (e = lane&7 rhs)
  const int e = lane & 7, cc = lane >> 3;
  for (int k = 39; k >= 0; --k) {
    float sr = 0.f, si = 0.f;
    for (int j = k + 1 + cc; j < 40; j += 8) {
      const float2 u = *(float2*)&ml[k * RS + j * 2];
      const float2 x = *(float2*)&ml[j * RS + (40 + e) * 2];
      sr += u.x * x.x - u.y * x.y;
      si += u.x * x.y + u.y * x.x;
    }
    sr += __shfl_xor(sr, 8);  si += __shfl_xor(si, 8);
    sr += __shfl_xor(sr, 16); si += __shfl_xor(si, 16);
    sr += __shfl_xor(sr, 32); si += __shfl_xor(si, 32);
    if (cc == 0) {
      const float2 pvt = *(float2*)&ml[k * RS + k * 2];
      const float den = pvt.x * pvt.x + pvt.y * pvt.y;
      const float inr = pvt.x / den, ini = -pvt.y / den;
      const float2 rhs = *(float2*)&ml[k * RS + (40 + e) * 2];
      const float nr = rhs.x - sr, ni = rhs.y - si;
      *(float2*)&ml[k * RS + (40 + e) * 2] =
          make_float2(nr * inr - ni * ini, nr * ini + ni * inr);
    }
    __syncthreads();
  }
  for (int idx = lane; idx < 320; idx += 64) {
    const int i = idx >> 3, ee = idx & 7;
    Gg[(size_t)bf * 320 + idx] = *(float2*)&ml[i * RS + (40 + ee) * 2];
  }
}

// ---------------------------------------------------------------------------
// K5: E[e,t] = Y[e,t] - sum_{p,d} G[p,d,e] * Y[d,t-3-p]
// 256 threads/block, one block per (b,f). Whole 512-frame panel staged in LDS
// (reads all come from LDS, so MODE 1 can overwrite Yg safely with no
// ordering tricks). G read as float4 LDS broadcasts inside a no-unroll tap
// loop -> register pressure stays bounded (the round-1 version spilled:
// VGPR=256, 4.7 GB scratch traffic, 2.67 ms).
// MODE 0: write power = mean_e |E|^2 (for iteration 2), discard E.
// MODE 1: overwrite Yg with E in place.
// ---------------------------------------------------------------------------
template <int MODE>
__global__ __launch_bounds__(256) void k_tail(float* __restrict__ Yg,
                                              const float2* __restrict__ Gg,
                                              float* __restrict__ pw) {
  const int bf = blockIdx.x;
  __shared__ float yl[TT * ROWQ];     // 40960 B
  __shared__ float gl[640];           // 2560 B: gl[((p*8+d)*8+e)*2 + ri]
  const int tid = threadIdx.x;
  for (int idx = tid; idx < 320; idx += 256) {
    float2 g = Gg[(size_t)bf * 320 + idx];
    *(float2*)&gl[idx * 2] = g;
  }
  const float4* ybase4 = (const float4*)(Yg + (size_t)bf * TT * 16);
  for (int fi = tid; fi < TT * 4; fi += 256) {
    const int row = fi >> 2, wq = fi & 3;
    *((float4*)&yl[row * ROWQ + wq * 4]) = ybase4[fi];
  }
  __syncthreads();

  const int t0 = tid;          // 0..255
  const int t1 = tid + 256;    // 256..511
  float acc[2][16];
  {
    const float* yr0 = &yl[t0 * ROWQ];
    const float* yr1 = &yl[t1 * ROWQ];
#pragma unroll
    for (int q = 0; q < 16; ++q) { acc[0][q] = yr0[q]; acc[1][q] = yr1[q]; }
  }
#pragma unroll 1
  for (int p = 0; p < TAPS; ++p) {
    const int rp0 = t0 - DELAY - p;        // may be <0 for tid<8
    const int rp1 = t1 - DELAY - p;        // always >=0
    const float* yrow0 = &yl[(rp0 >= 0 ? rp0 : 0) * ROWQ];
    const float* yrow1 = &yl[rp1 * ROWQ];
    const float m0 = (rp0 >= 0) ? 1.0f : 0.0f;
    const float* gp = &gl[p * 128];
#pragma unroll
    for (int d = 0; d < CHN; ++d) {
      const float y0r = m0 * yrow0[2 * d], y0i = m0 * yrow0[2 * d + 1];
      const float y1r = yrow1[2 * d],      y1i = yrow1[2 * d + 1];
      const float4 g0 = *(const float4*)&gp[d * 16 + 0];   // e0,e1
      const float4 g1 = *(const float4*)&gp[d * 16 + 4];   // e2,e3
      const float4 g2 = *(const float4*)&gp[d * 16 + 8];   // e4,e5
      const float4 g3 = *(const float4*)&gp[d * 16 + 12];  // e6,e7
      const float gr[8] = {g0.x, g0.z, g1.x, g1.z, g2.x, g2.z, g3.x, g3.z};
      const float gi[8] = {g0.y, g0.w, g1.y, g1.w, g2.y, g2.w, g3.y, g3.w};
#pragma unroll
      for (int ee = 0; ee < 8; ++ee) {
        acc[0][2 * ee]     -= gr[ee] * y0r - gi[ee] * y0i;
        acc[0][2 * ee + 1] -= gr[ee] * y0i + gi[ee] * y0r;
        acc[1][2 * ee]     -= gr[ee] * y1r - gi[ee] * y1i;
        acc[1][2 * ee + 1] -= gr[ee] * y1i + gi[ee] * y1r;
      }
    }
  }
  float* ybase = Yg + (size_t)bf * TT * 16;
  if (MODE == 0) {
#pragma unroll
    for (int s = 0; s < 2; ++s) {
      const int t = tid + s * 256;
      float ss = 0.f;
#pragma unroll
      for (int q = 0; q < 16; ++q) ss += acc[s][q] * acc[s][q];
      pw[(size_t)bf * TT + t] = ss * (1.0f / CHN);
    }
  } else {
#pragma unroll
    for (int s = 0; s < 2; ++s) {
      const int t = tid + s * 256;
      float4* dst = (float4*)(ybase + (size_t)t * 16);
      dst[0] = make_float4(acc[s][0], acc[s][1], acc[s][2], acc[s][3]);
      dst[1] = make_float4(acc[s][4], acc[s][5], acc[s][6], acc[s][7]);
      dst[2] = make_float4(acc[s][8], acc[s][9], acc[s][10], acc[s][11]);
      dst[3] = make_float4(acc[s][12], acc[s][13], acc[s][14], acc[s][15]);
    }
  }
}

// ---------------------------------------------------------------------------
// K6: Yg[b][f][t][c][2] -> out[b][t][c][f][2]
// ---------------------------------------------------------------------------
__global__ void k_unpack(const float* __restrict__ Yg, float* __restrict__ out) {
  const int ft = blockIdx.x, tt = blockIdx.y, b = blockIdx.z;
  const int f0 = ft * 32, t0 = tt * 16;
  __shared__ float ls[32 * 258];
  const int tid = threadIdx.x;
  for (int ff = 0; ff < 32; ++ff) {
    const int fg = f0 + ff;
    if (fg >= FF) break;
    ls[ff * 258 + tid] = Yg[(((size_t)b * FF + fg) * TT + t0) * 16 + tid];
  }
  __syncthreads();
  const int l = tid & 31, r = tid >> 5;
  const int fg = f0 + l;
  if (fg < FF) {
    for (int k = 0; k < 16; ++k) {
      const int task = r + 8 * k;          // 0..127 -> (t,c)
      const int t = task >> 3, c = task & 7;
      const float2 v = *(float2*)&ls[l * 258 + t * 16 + c * 2];
      *(float2*)&out[((((size_t)b * TT + t0 + t) * CHN + c) * FF + fg) * 2] = v;
    }
  }
}

// ---------------------------------------------------------------------------
extern "C" void kernel_launch(void* const* d_in, const int* in_sizes, int n_in,
                              void* d_out, int out_size, void* d_ws, size_t ws_size,
                              hipStream_t stream) {
  const float* re = (const float*)d_in[0];
  const float* im = (const float*)d_in[1];
  float* ws = (float*)d_ws;

  float*  Yg = ws;                                        // NBF*T*16 floats  (67.4 MB)
  float*  pw = Yg + (size_t)NBF * TT * 16;                // NBF*T            (4.2 MB)
  float2* Mg = (float2*)(pw + (size_t)NBF * TT);          // NBF*40*48 cplx   (31.6 MB)
  float2* Gg = Mg + (size_t)NBF * 40 * MC;                // NBF*320 cplx     (5.3 MB)
  float*  out = (float*)d_out;

  const dim3 gridT(9, 32, BB);
  k_pack<<<gridT, 256, 0, stream>>>(re, im, Yg);

  {
    const int n = NBF * TT;
    k_power0<<<(n + 255) / 256, 256, 0, stream>>>(Yg, pw);
  }

  for (int iter = 0; iter < 2; ++iter) {
    k_corr<<<NBF, 64, 0, stream>>>(Yg, pw, Mg);
    k_solve<<<NBF, 64, 0, stream>>>(Mg, Gg);
    if (iter == 0)
      k_tail<0><<<NBF, 256, 0, stream>>>(Yg, Gg, pw);   // -> power for iter 2
    else
      k_tail<1><<<NBF, 256, 0, stream>>>(Yg, Gg, pw);   // -> E in place
  }

  k_unpack<<<gridT, 256, 0, stream>>>(Yg, out);
}

// Round 3
// 1232.637 us; speedup vs baseline: 4.0415x; 1.2017x over previous
//
#include <hip/hip_runtime.h>

// Problem constants (B,T,C,F fixed by harness)
constexpr int BB = 8;
constexpr int TT = 512;
constexpr int CHN = 8;
constexpr int FF = 257;
constexpr int TAPS = 5;
constexpr int DELAY = 3;
constexpr int NBF = BB * FF;          // 2056 independent (b,f) systems
constexpr int ROWQ = 20;              // k_tail LDS floats per t-row
constexpr int MC = 48;                // augmented matrix cols (40 R + 8 rhs)
constexpr int RS = 98;                // solver LDS row stride in floats (48*2 + 2 pad)

// ---------------------------------------------------------------------------
// K1: (B,T,C,F) re/im -> Yg[b][f][t][c][2]  (time-contiguous complex layout)
// ---------------------------------------------------------------------------
__global__ void k_pack(const float* __restrict__ re, const float* __restrict__ im,
                       float* __restrict__ Yg) {
  const int ft = blockIdx.x, tt = blockIdx.y, b = blockIdx.z;
  const int f0 = ft * 32, t0 = tt * 16;
  __shared__ float ls[32 * 258];
  const int tid = threadIdx.x;
  const int l = tid & 31;   // f lane
  const int r = tid >> 5;   // 0..7
  const int f = f0 + l;
  if (f < FF) {
    for (int k = 0; k < 32; ++k) {
      const int task = r + 8 * k;       // 0..255 -> (t,c,ri)
      const int ri = task & 1;
      const int c  = (task >> 1) & 7;
      const int t  = task >> 4;         // 0..15
      const float* src = ri ? im : re;
      const float v = src[(((size_t)b * TT + t0 + t) * CHN + c) * FF + f];
      ls[l * 258 + (t * 16 + c * 2 + ri)] = v;
    }
  }
  __syncthreads();
  for (int ff = 0; ff < 32; ++ff) {
    const int fg = f0 + ff;
    if (fg >= FF) break;
    Yg[(((size_t)b * FF + fg) * TT + t0) * 16 + tid] = ls[ff * 258 + tid];
  }
}

// ---------------------------------------------------------------------------
// K2: initial power[b][f][t] = mean_c |Y|^2
// ---------------------------------------------------------------------------
__global__ void k_power0(const float* __restrict__ Yg, float* __restrict__ pw) {
  const size_t idx = (size_t)blockIdx.x * blockDim.x + threadIdx.x;
  if (idx >= (size_t)NBF * TT) return;
  const float4* y4 = (const float4*)(Yg + idx * 16);
  float s = 0.f;
#pragma unroll
  for (int k = 0; k < 4; ++k) {
    float4 v = y4[k];
    s += v.x * v.x + v.y * v.y + v.z * v.z + v.w * v.w;
  }
  pw[idx] = s * (1.0f / CHN);
}

// ---------------------------------------------------------------------------
// K3: per (b,f) accumulate M = [R | b] (40x48 complex).
//   M[i=(p,d)][j] = sum_{t>=7} w[t] * conj(Y[d,t-3-p]) * z_j[t]
//   z_j = Y[e,t-3-q] for j=(q,e)<40, z_j = Y[e,t] for j=40+e.
// 4 waves per block (one block per (b,f)); each wave accumulates a 128-t
// quarter over the full 512-t panel staged planar (re|im) in LDS; partials
// reduced via 2-round LDS tree. 60 active lanes own an 8x4 complex tile.
// LDS = 34.8 KB -> 4 blocks/CU (16 waves/CU).
// ---------------------------------------------------------------------------
__global__ __launch_bounds__(256) void k_corr(const float* __restrict__ Yg,
                                              const float* __restrict__ pw,
                                              float2* __restrict__ Mg) {
  const int bf = blockIdx.x;
  __shared__ float lds[8192 + 512];          // re[4096] | im[4096] | wl[512]
  float* pre = lds;
  float* pim = lds + 4096;
  float* wl  = lds + 8192;
  const int tid = threadIdx.x;
  const int wave = tid >> 6, lane = tid & 63;

  for (int t = tid; t < TT; t += 256) {
    const float p = pw[(size_t)bf * TT + t];
    wl[t] = (t >= DELAY + TAPS - 1) ? (1.0f / fmaxf(p, 1e-10f)) : 0.0f;
  }
  // stage interleaved global panel -> planar LDS panels
  const float4* ybase4 = (const float4*)(Yg + (size_t)bf * TT * 16);
  for (int fi = tid; fi < TT * 4; fi += 256) {
    const int t = fi >> 2, q = fi & 3;       // q = complex pair index
    const float4 v = ybase4[fi];
    *(float2*)&pre[t * 8 + 2 * q] = make_float2(v.x, v.z);
    *(float2*)&pim[t * 8 + 2 * q] = make_float2(v.y, v.w);
  }
  __syncthreads();

  const bool active = lane < 60;
  const int it = lane / 12;                 // 0..4  (p of x-block)
  const int jt = lane - it * 12;            // 0..11 (4-col z-block)
  const int xoff = DELAY + it;              // x row = t - xoff
  const int zoff = (jt < 10) ? (DELAY + (jt >> 1)) : 0;
  const int ze0  = (jt < 10) ? ((jt & 1) * 4) : ((jt - 10) * 4);

  float accr[8][4], acci[8][4];
#pragma unroll
  for (int l = 0; l < 8; ++l)
#pragma unroll
    for (int m = 0; m < 4; ++m) { accr[l][m] = 0.f; acci[l][m] = 0.f; }

  const int t_lo = (wave == 0) ? (DELAY + TAPS - 1) : wave * 128;
  const int t_hi = (wave + 1) * 128;
  if (active) {
    const float* xre = &pre[(t_lo - xoff) * 8];
    const float* xim = &pim[(t_lo - xoff) * 8];
    const float* zre = &pre[(t_lo - zoff) * 8 + ze0];
    const float* zim = &pim[(t_lo - zoff) * 8 + ze0];
    for (int t = t_lo; t < t_hi; ++t) {
      const float w = wl[t];
      const float4 xr0 = *(const float4*)xre;
      const float4 xr1 = *(const float4*)(xre + 4);
      const float4 xi0 = *(const float4*)xim;
      const float4 xi1 = *(const float4*)(xim + 4);
      const float4 zr = *(const float4*)zre;
      const float4 zi = *(const float4*)zim;
      const float zwr[4] = {w * zr.x, w * zr.y, w * zr.z, w * zr.w};
      const float zwi[4] = {w * zi.x, w * zi.y, w * zi.z, w * zi.w};
      const float xrA[8] = {xr0.x, xr0.y, xr0.z, xr0.w, xr1.x, xr1.y, xr1.z, xr1.w};
      const float xiA[8] = {xi0.x, xi0.y, xi0.z, xi0.w, xi1.x, xi1.y, xi1.z, xi1.w};
#pragma unroll
      for (int l = 0; l < 8; ++l) {
#pragma unroll
        for (int m = 0; m < 4; ++m) {
          accr[l][m] += xrA[l] * zwr[m] + xiA[l] * zwi[m];
          acci[l][m] += xrA[l] * zwi[m] - xiA[l] * zwr[m];
        }
      }
      xre += 8; xim += 8; zre += 8; zim += 8;
    }
  }

  // ---- reduce 4 wave-partials (reuse panel LDS; stride 66 floats/lane) ----
  __syncthreads();
  if ((wave == 1 || wave == 3) && active) {
    float2* dst = (float2*)(lds + (wave >> 1) * 3960 + lane * 66);
#pragma unroll
    for (int l = 0; l < 8; ++l)
#pragma unroll
      for (int m = 0; m < 4; ++m) dst[l * 4 + m] = make_float2(accr[l][m], acci[l][m]);
  }
  __syncthreads();
  if ((wave == 0 || wave == 2) && active) {
    const float2* src = (const float2*)(lds + (wave >> 1) * 3960 + lane * 66);
#pragma unroll
    for (int l = 0; l < 8; ++l)
#pragma unroll
      for (int m = 0; m < 4; ++m) {
        const float2 v = src[l * 4 + m];
        accr[l][m] += v.x; acci[l][m] += v.y;
      }
  }
  __syncthreads();
  if (wave == 2 && active) {
    float2* dst = (float2*)(lds + lane * 66);
#pragma unroll
    for (int l = 0; l < 8; ++l)
#pragma unroll
      for (int m = 0; m < 4; ++m) dst[l * 4 + m] = make_float2(accr[l][m], acci[l][m]);
  }
  __syncthreads();
  if (wave == 0 && active) {
    const float2* src = (const float2*)(lds + lane * 66);
#pragma unroll
    for (int l = 0; l < 8; ++l) {
      const int i = it * 8 + l;
#pragma unroll
      for (int m = 0; m < 4; ++m) {
        const int j = jt * 4 + m;
        const float2 v = src[l * 4 + m];
        float rr = accr[l][m] + v.x;
        if (i == j) rr += 1e-10f;           // + eps * I on the R diagonal
        Mg[((size_t)bf * 40 + i) * MC + j] = make_float2(rr, acci[l][m] + v.y);
      }
    }
  }
}

// ---------------------------------------------------------------------------
// K4: per (b,f) solve (R+eps I) G = b via unpivoted elimination (R is HPD).
// One wave per system, in LDS.
// ---------------------------------------------------------------------------
__global__ __launch_bounds__(64) void k_solve(const float2* __restrict__ Mg,
                                              float2* __restrict__ Gg) {
  const int bf = blockIdx.x;
  __shared__ float ml[40 * RS];
  const int lane = threadIdx.x;
  for (int idx = lane; idx < 40 * MC; idx += 64) {
    const int i = idx / MC, j = idx - i * MC;
    float2 v = Mg[((size_t)bf * 40 + i) * MC + j];
    *(float2*)&ml[i * RS + j * 2] = v;
  }
  __syncthreads();
  const int li = lane >> 3, lj = lane & 7;
  // forward elimination
  for (int k = 0; k < 40; ++k) {
    const float2 pv = *(float2*)&ml[k * RS + k * 2];
    const float den = pv.x * pv.x + pv.y * pv.y;
    const float inr = pv.x / den, ini = -pv.y / den;
    for (int i = k + 1 + li; i < 40; i += 8) {
      const float2 aik = *(float2*)&ml[i * RS + k * 2];
      const float fr = aik.x * inr - aik.y * ini;
      const float fi = aik.x * ini + aik.y * inr;
      for (int j = k + 1 + lj; j < MC; j += 8) {
        const float2 ak = *(float2*)&ml[k * RS + j * 2];
        float2 ai = *(float2*)&ml[i * RS + j * 2];
        ai.x -= fr * ak.x - fi * ak.y;
        ai.y -= fr * ak.y + fi * ak.x;
        *(float2*)&ml[i * RS + j * 2] = ai;
      }
    }
    __syncthreads();
  }
  // back substitution: lanes (cc = lane>>3 partial-chunks) x (e = lane&7 rhs)
  const int e = lane & 7, cc = lane >> 3;
  for (int k = 39; k >= 0; --k) {
    float sr = 0.f, si = 0.f;
    for (int j = k + 1 + cc; j < 40; j += 8) {
      const float2 u = *(float2*)&ml[k * RS + j * 2];
      const float2 x = *(float2*)&ml[j * RS + (40 + e) * 2];
      sr += u.x * x.x - u.y * x.y;
      si += u.x * x.y + u.y * x.x;
    }
    sr += __shfl_xor(sr, 8);  si += __shfl_xor(si, 8);
    sr += __shfl_xor(sr, 16); si += __shfl_xor(si, 16);
    sr += __shfl_xor(sr, 32); si += __shfl_xor(si, 32);
    if (cc == 0) {
      const float2 pvt = *(float2*)&ml[k * RS + k * 2];
      const float den = pvt.x * pvt.x + pvt.y * pvt.y;
      const float inr = pvt.x / den, ini = -pvt.y / den;
      const float2 rhs = *(float2*)&ml[k * RS + (40 + e) * 2];
      const float nr = rhs.x - sr, ni = rhs.y - si;
      *(float2*)&ml[k * RS + (40 + e) * 2] =
          make_float2(nr * inr - ni * ini, nr * ini + ni * inr);
    }
    __syncthreads();
  }
  for (int idx = lane; idx < 320; idx += 64) {
    const int i = idx >> 3, ee = idx & 7;
    Gg[(size_t)bf * 320 + idx] = *(float2*)&ml[i * RS + (40 + ee) * 2];
  }
}

// ---------------------------------------------------------------------------
// K5: E[e,t] = Y[e,t] - sum_{p,d} G[p,d,e] * Y[d,t-3-p]
// 256 threads/block, one block per (b,f). Whole 512-frame panel staged in LDS.
// MODE 0: write power = mean_e |E|^2 (for iteration 2), discard E.
// MODE 1: overwrite Yg with E in place.
// ---------------------------------------------------------------------------
template <int MODE>
__global__ __launch_bounds__(256) void k_tail(float* __restrict__ Yg,
                                              const float2* __restrict__ Gg,
                                              float* __restrict__ pw) {
  const int bf = blockIdx.x;
  __shared__ float yl[TT * ROWQ];     // 40960 B
  __shared__ float gl[640];           // 2560 B: gl[((p*8+d)*8+e)*2 + ri]
  const int tid = threadIdx.x;
  for (int idx = tid; idx < 320; idx += 256) {
    float2 g = Gg[(size_t)bf * 320 + idx];
    *(float2*)&gl[idx * 2] = g;
  }
  const float4* ybase4 = (const float4*)(Yg + (size_t)bf * TT * 16);
  for (int fi = tid; fi < TT * 4; fi += 256) {
    const int row = fi >> 2, wq = fi & 3;
    *((float4*)&yl[row * ROWQ + wq * 4]) = ybase4[fi];
  }
  __syncthreads();

  const int t0 = tid;          // 0..255
  const int t1 = tid + 256;    // 256..511
  float acc[2][16];
  {
    const float* yr0 = &yl[t0 * ROWQ];
    const float* yr1 = &yl[t1 * ROWQ];
#pragma unroll
    for (int q = 0; q < 16; ++q) { acc[0][q] = yr0[q]; acc[1][q] = yr1[q]; }
  }
#pragma unroll 1
  for (int p = 0; p < TAPS; ++p) {
    const int rp0 = t0 - DELAY - p;        // may be <0 for tid<8
    const int rp1 = t1 - DELAY - p;        // always >=0
    const float* yrow0 = &yl[(rp0 >= 0 ? rp0 : 0) * ROWQ];
    const float* yrow1 = &yl[rp1 * ROWQ];
    const float m0 = (rp0 >= 0) ? 1.0f : 0.0f;
    const float* gp = &gl[p * 128];
#pragma unroll
    for (int d = 0; d < CHN; ++d) {
      const float y0r = m0 * yrow0[2 * d], y0i = m0 * yrow0[2 * d + 1];
      const float y1r = yrow1[2 * d],      y1i = yrow1[2 * d + 1];
      const float4 g0 = *(const float4*)&gp[d * 16 + 0];   // e0,e1
      const float4 g1 = *(const float4*)&gp[d * 16 + 4];   // e2,e3
      const float4 g2 = *(const float4*)&gp[d * 16 + 8];   // e4,e5
      const float4 g3 = *(const float4*)&gp[d * 16 + 12];  // e6,e7
      const float gr[8] = {g0.x, g0.z, g1.x, g1.z, g2.x, g2.z, g3.x, g3.z};
      const float gi[8] = {g0.y, g0.w, g1.y, g1.w, g2.y, g2.w, g3.y, g3.w};
#pragma unroll
      for (int ee = 0; ee < 8; ++ee) {
        acc[0][2 * ee]     -= gr[ee] * y0r - gi[ee] * y0i;
        acc[0][2 * ee + 1] -= gr[ee] * y0i + gi[ee] * y0r;
        acc[1][2 * ee]     -= gr[ee] * y1r - gi[ee] * y1i;
        acc[1][2 * ee + 1] -= gr[ee] * y1i + gi[ee] * y1r;
      }
    }
  }
  float* ybase = Yg + (size_t)bf * TT * 16;
  if (MODE == 0) {
#pragma unroll
    for (int s = 0; s < 2; ++s) {
      const int t = tid + s * 256;
      float ss = 0.f;
#pragma unroll
      for (int q = 0; q < 16; ++q) ss += acc[s][q] * acc[s][q];
      pw[(size_t)bf * TT + t] = ss * (1.0f / CHN);
    }
  } else {
#pragma unroll
    for (int s = 0; s < 2; ++s) {
      const int t = tid + s * 256;
      float4* dst = (float4*)(ybase + (size_t)t * 16);
      dst[0] = make_float4(acc[s][0], acc[s][1], acc[s][2], acc[s][3]);
      dst[1] = make_float4(acc[s][4], acc[s][5], acc[s][6], acc[s][7]);
      dst[2] = make_float4(acc[s][8], acc[s][9], acc[s][10], acc[s][11]);
      dst[3] = make_float4(acc[s][12], acc[s][13], acc[s][14], acc[s][15]);
    }
  }
}

// ---------------------------------------------------------------------------
// K6: Yg[b][f][t][c][2] -> out[b][t][c][f][2]
// ---------------------------------------------------------------------------
__global__ void k_unpack(const float* __restrict__ Yg, float* __restrict__ out) {
  const int ft = blockIdx.x, tt = blockIdx.y, b = blockIdx.z;
  const int f0 = ft * 32, t0 = tt * 16;
  __shared__ float ls[32 * 258];
  const int tid = threadIdx.x;
  for (int ff = 0; ff < 32; ++ff) {
    const int fg = f0 + ff;
    if (fg >= FF) break;
    ls[ff * 258 + tid] = Yg[(((size_t)b * FF + fg) * TT + t0) * 16 + tid];
  }
  __syncthreads();
  const int l = tid & 31, r = tid >> 5;
  const int fg = f0 + l;
  if (fg < FF) {
    for (int k = 0; k < 16; ++k) {
      const int task = r + 8 * k;          // 0..127 -> (t,c)
      const int t = task >> 3, c = task & 7;
      const float2 v = *(float2*)&ls[l * 258 + t * 16 + c * 2];
      *(float2*)&out[((((size_t)b * TT + t0 + t) * CHN + c) * FF + fg) * 2] = v;
    }
  }
}

// ---------------------------------------------------------------------------
extern "C" void kernel_launch(void* const* d_in, const int* in_sizes, int n_in,
                              void* d_out, int out_size, void* d_ws, size_t ws_size,
                              hipStream_t stream) {
  const float* re = (const float*)d_in[0];
  const float* im = (const float*)d_in[1];
  float* ws = (float*)d_ws;

  float*  Yg = ws;                                        // NBF*T*16 floats  (67.4 MB)
  float*  pw = Yg + (size_t)NBF * TT * 16;                // NBF*T            (4.2 MB)
  float2* Mg = (float2*)(pw + (size_t)NBF * TT);          // NBF*40*48 cplx   (31.6 MB)
  float2* Gg = Mg + (size_t)NBF * 40 * MC;                // NBF*320 cplx     (5.3 MB)
  float*  out = (float*)d_out;

  const dim3 gridT(9, 32, BB);
  k_pack<<<gridT, 256, 0, stream>>>(re, im, Yg);

  {
    const int n = NBF * TT;
    k_power0<<<(n + 255) / 256, 256, 0, stream>>>(Yg, pw);
  }

  for (int iter = 0; iter < 2; ++iter) {
    k_corr<<<NBF, 256, 0, stream>>>(Yg, pw, Mg);
    k_solve<<<NBF, 64, 0, stream>>>(Mg, Gg);
    if (iter == 0)
      k_tail<0><<<NBF, 256, 0, stream>>>(Yg, Gg, pw);   // -> power for iter 2
    else
      k_tail<1><<<NBF, 256, 0, stream>>>(Yg, Gg, pw);   // -> E in place
  }

  k_unpack<<<gridT, 256, 0, stream>>>(Yg, out);
}

// Round 4
// 1225.282 us; speedup vs baseline: 4.0658x; 1.0060x over previous
//
#include <hip/hip_runtime.h>

// Problem constants (B,T,C,F fixed by harness)
constexpr int BB = 8;
constexpr int TT = 512;
constexpr int CHN = 8;
constexpr int FF = 257;
constexpr int TAPS = 5;
constexpr int DELAY = 3;
constexpr int NBF = BB * FF;          // 2056 independent (b,f) systems
constexpr int ROWQ = 20;              // k_tail LDS floats per t-row
constexpr int MC = 48;                // augmented matrix cols (40 R + 8 rhs)
constexpr int RS = 98;                // solver LDS row stride in floats (48*2 + 2 pad)

// ---------------------------------------------------------------------------
// K1: (B,T,C,F) re/im -> Yg[b][f][t][c][2]  (time-contiguous complex layout)
// ---------------------------------------------------------------------------
__global__ void k_pack(const float* __restrict__ re, const float* __restrict__ im,
                       float* __restrict__ Yg) {
  const int ft = blockIdx.x, tt = blockIdx.y, b = blockIdx.z;
  const int f0 = ft * 32, t0 = tt * 16;
  __shared__ float ls[32 * 258];
  const int tid = threadIdx.x;
  const int l = tid & 31;   // f lane
  const int r = tid >> 5;   // 0..7
  const int f = f0 + l;
  if (f < FF) {
    for (int k = 0; k < 32; ++k) {
      const int task = r + 8 * k;       // 0..255 -> (t,c,ri)
      const int ri = task & 1;
      const int c  = (task >> 1) & 7;
      const int t  = task >> 4;         // 0..15
      const float* src = ri ? im : re;
      const float v = src[(((size_t)b * TT + t0 + t) * CHN + c) * FF + f];
      ls[l * 258 + (t * 16 + c * 2 + ri)] = v;
    }
  }
  __syncthreads();
  for (int ff = 0; ff < 32; ++ff) {
    const int fg = f0 + ff;
    if (fg >= FF) break;
    Yg[(((size_t)b * FF + fg) * TT + t0) * 16 + tid] = ls[ff * 258 + tid];
  }
}

// ---------------------------------------------------------------------------
// K2: initial power[b][f][t] = mean_c |Y|^2
// ---------------------------------------------------------------------------
__global__ void k_power0(const float* __restrict__ Yg, float* __restrict__ pw) {
  const size_t idx = (size_t)blockIdx.x * blockDim.x + threadIdx.x;
  if (idx >= (size_t)NBF * TT) return;
  const float4* y4 = (const float4*)(Yg + idx * 16);
  float s = 0.f;
#pragma unroll
  for (int k = 0; k < 4; ++k) {
    float4 v = y4[k];
    s += v.x * v.x + v.y * v.y + v.z * v.z + v.w * v.w;
  }
  pw[idx] = s * (1.0f / CHN);
}

// ---------------------------------------------------------------------------
// K3: per (b,f) accumulate M = [R | b] (40x48 complex).
//   M[i=(p,d)][j] = sum_{t>=7} w[t] * conj(Y[d,t-3-p]) * z_j[t]
//   z_j = Y[e,t-3-q] for j=(q,e)<40, z_j = Y[e,t] for j=40+e.
// 4 waves per block (one block per (b,f)); each wave accumulates a 128-t
// quarter over the full 512-t panel staged planar (re|im) in LDS; partials
// reduced via 2-round LDS tree. 60 active lanes own an 8x4 complex tile.
// __launch_bounds__(256, 4): 4 waves/EU -> VGPR cap 128, so the 64
// accumulator floats stay in true VGPRs (round-3 compiled at VGPR=64 and
// shunted accumulators to AGPRs -> 3x VALU inflation via accvgpr moves).
// ---------------------------------------------------------------------------
__global__ __launch_bounds__(256, 4) void k_corr(const float* __restrict__ Yg,
                                                 const float* __restrict__ pw,
                                                 float2* __restrict__ Mg) {
  const int bf = blockIdx.x;
  __shared__ float lds[8192 + 512];          // re[4096] | im[4096] | wl[512]
  float* pre = lds;
  float* pim = lds + 4096;
  float* wl  = lds + 8192;
  const int tid = threadIdx.x;
  const int wave = tid >> 6, lane = tid & 63;

  for (int t = tid; t < TT; t += 256) {
    const float p = pw[(size_t)bf * TT + t];
    wl[t] = (t >= DELAY + TAPS - 1) ? (1.0f / fmaxf(p, 1e-10f)) : 0.0f;
  }
  // stage interleaved global panel -> planar LDS panels
  const float4* ybase4 = (const float4*)(Yg + (size_t)bf * TT * 16);
  for (int fi = tid; fi < TT * 4; fi += 256) {
    const int t = fi >> 2, q = fi & 3;       // q = complex pair index
    const float4 v = ybase4[fi];
    *(float2*)&pre[t * 8 + 2 * q] = make_float2(v.x, v.z);
    *(float2*)&pim[t * 8 + 2 * q] = make_float2(v.y, v.w);
  }
  __syncthreads();

  const bool active = lane < 60;
  const int it = lane / 12;                 // 0..4  (p of x-block)
  const int jt = lane - it * 12;            // 0..11 (4-col z-block)
  const int xoff = DELAY + it;              // x row = t - xoff
  const int zoff = (jt < 10) ? (DELAY + (jt >> 1)) : 0;
  const int ze0  = (jt < 10) ? ((jt & 1) * 4) : ((jt - 10) * 4);

  float accr[8][4], acci[8][4];
#pragma unroll
  for (int l = 0; l < 8; ++l)
#pragma unroll
    for (int m = 0; m < 4; ++m) { accr[l][m] = 0.f; acci[l][m] = 0.f; }

  const int t_lo = (wave == 0) ? (DELAY + TAPS - 1) : wave * 128;
  const int t_hi = (wave + 1) * 128;
  if (active) {
    const float* xre = &pre[(t_lo - xoff) * 8];
    const float* xim = &pim[(t_lo - xoff) * 8];
    const float* zre = &pre[(t_lo - zoff) * 8 + ze0];
    const float* zim = &pim[(t_lo - zoff) * 8 + ze0];
    for (int t = t_lo; t < t_hi; ++t) {
      const float w = wl[t];
      const float4 xr0 = *(const float4*)xre;
      const float4 xr1 = *(const float4*)(xre + 4);
      const float4 xi0 = *(const float4*)xim;
      const float4 xi1 = *(const float4*)(xim + 4);
      const float4 zr = *(const float4*)zre;
      const float4 zi = *(const float4*)zim;
      const float zwr[4] = {w * zr.x, w * zr.y, w * zr.z, w * zr.w};
      const float zwi[4] = {w * zi.x, w * zi.y, w * zi.z, w * zi.w};
      const float xrA[8] = {xr0.x, xr0.y, xr0.z, xr0.w, xr1.x, xr1.y, xr1.z, xr1.w};
      const float xiA[8] = {xi0.x, xi0.y, xi0.z, xi0.w, xi1.x, xi1.y, xi1.z, xi1.w};
#pragma unroll
      for (int l = 0; l < 8; ++l) {
#pragma unroll
        for (int m = 0; m < 4; ++m) {
          accr[l][m] += xrA[l] * zwr[m] + xiA[l] * zwi[m];
          acci[l][m] += xrA[l] * zwi[m] - xiA[l] * zwr[m];
        }
      }
      xre += 8; xim += 8; zre += 8; zim += 8;
    }
  }

  // ---- reduce 4 wave-partials (reuse panel LDS; stride 66 floats/lane) ----
  __syncthreads();
  if ((wave == 1 || wave == 3) && active) {
    float2* dst = (float2*)(lds + (wave >> 1) * 3960 + lane * 66);
#pragma unroll
    for (int l = 0; l < 8; ++l)
#pragma unroll
      for (int m = 0; m < 4; ++m) dst[l * 4 + m] = make_float2(accr[l][m], acci[l][m]);
  }
  __syncthreads();
  if ((wave == 0 || wave == 2) && active) {
    const float2* src = (const float2*)(lds + (wave >> 1) * 3960 + lane * 66);
#pragma unroll
    for (int l = 0; l < 8; ++l)
#pragma unroll
      for (int m = 0; m < 4; ++m) {
        const float2 v = src[l * 4 + m];
        accr[l][m] += v.x; acci[l][m] += v.y;
      }
  }
  __syncthreads();
  if (wave == 2 && active) {
    float2* dst = (float2*)(lds + lane * 66);
#pragma unroll
    for (int l = 0; l < 8; ++l)
#pragma unroll
      for (int m = 0; m < 4; ++m) dst[l * 4 + m] = make_float2(accr[l][m], acci[l][m]);
  }
  __syncthreads();
  if (wave == 0 && active) {
    const float2* src = (const float2*)(lds + lane * 66);
#pragma unroll
    for (int l = 0; l < 8; ++l) {
      const int i = it * 8 + l;
#pragma unroll
      for (int m = 0; m < 4; ++m) {
        const int j = jt * 4 + m;
        const float2 v = src[l * 4 + m];
        float rr = accr[l][m] + v.x;
        if (i == j) rr += 1e-10f;           // + eps * I on the R diagonal
        Mg[((size_t)bf * 40 + i) * MC + j] = make_float2(rr, acci[l][m] + v.y);
      }
    }
  }
}

// ---------------------------------------------------------------------------
// K4: per (b,f) solve (R+eps I) G = b via unpivoted elimination (R is HPD).
// One wave per system, in LDS.
// ---------------------------------------------------------------------------
__global__ __launch_bounds__(64) void k_solve(const float2* __restrict__ Mg,
                                              float2* __restrict__ Gg) {
  const int bf = blockIdx.x;
  __shared__ float ml[40 * RS];
  const int lane = threadIdx.x;
  for (int idx = lane; idx < 40 * MC; idx += 64) {
    const int i = idx / MC, j = idx - i * MC;
    float2 v = Mg[((size_t)bf * 40 + i) * MC + j];
    *(float2*)&ml[i * RS + j * 2] = v;
  }
  __syncthreads();
  const int li = lane >> 3, lj = lane & 7;
  // forward elimination
  for (int k = 0; k < 40; ++k) {
    const float2 pv = *(float2*)&ml[k * RS + k * 2];
    const float den = pv.x * pv.x + pv.y * pv.y;
    const float inr = pv.x / den, ini = -pv.y / den;
    for (int i = k + 1 + li; i < 40; i += 8) {
      const float2 aik = *(float2*)&ml[i * RS + k * 2];
      const float fr = aik.x * inr - aik.y * ini;
      const float fi = aik.x * ini + aik.y * inr;
      for (int j = k + 1 + lj; j < MC; j += 8) {
        const float2 ak = *(float2*)&ml[k * RS + j * 2];
        float2 ai = *(float2*)&ml[i * RS + j * 2];
        ai.x -= fr * ak.x - fi * ak.y;
        ai.y -= fr * ak.y + fi * ak.x;
        *(float2*)&ml[i * RS + j * 2] = ai;
      }
    }
    __syncthreads();
  }
  // back substitution: lanes (cc = lane>>3 partial-chunks) x (e = lane&7 rhs)
  const int e = lane & 7, cc = lane >> 3;
  for (int k = 39; k >= 0; --k) {
    float sr = 0.f, si = 0.f;
    for (int j = k + 1 + cc; j < 40; j += 8) {
      const float2 u = *(float2*)&ml[k * RS + j * 2];
      const float2 x = *(float2*)&ml[j * RS + (40 + e) * 2];
      sr += u.x * x.x - u.y * x.y;
      si += u.x * x.y + u.y * x.x;
    }
    sr += __shfl_xor(sr, 8);  si += __shfl_xor(si, 8);
    sr += __shfl_xor(sr, 16); si += __shfl_xor(si, 16);
    sr += __shfl_xor(sr, 32); si += __shfl_xor(si, 32);
    if (cc == 0) {
      const float2 pvt = *(float2*)&ml[k * RS + k * 2];
      const float den = pvt.x * pvt.x + pvt.y * pvt.y;
      const float inr = pvt.x / den, ini = -pvt.y / den;
      const float2 rhs = *(float2*)&ml[k * RS + (40 + e) * 2];
      const float nr = rhs.x - sr, ni = rhs.y - si;
      *(float2*)&ml[k * RS + (40 + e) * 2] =
          make_float2(nr * inr - ni * ini, nr * ini + ni * inr);
    }
    __syncthreads();
  }
  for (int idx = lane; idx < 320; idx += 64) {
    const int i = idx >> 3, ee = idx & 7;
    Gg[(size_t)bf * 320 + idx] = *(float2*)&ml[i * RS + (40 + ee) * 2];
  }
}

// ---------------------------------------------------------------------------
// K5: E[e,t] = Y[e,t] - sum_{p,d} G[p,d,e] * Y[d,t-3-p]
// 256 threads/block, one block per (b,f). Whole 512-frame panel staged in LDS.
// MODE 0: write power = mean_e |E|^2 (for iteration 2), discard E.
// MODE 1: overwrite Yg with E in place.
// ---------------------------------------------------------------------------
template <int MODE>
__global__ __launch_bounds__(256) void k_tail(float* __restrict__ Yg,
                                              const float2* __restrict__ Gg,
                                              float* __restrict__ pw) {
  const int bf = blockIdx.x;
  __shared__ float yl[TT * ROWQ];     // 40960 B
  __shared__ float gl[640];           // 2560 B: gl[((p*8+d)*8+e)*2 + ri]
  const int tid = threadIdx.x;
  for (int idx = tid; idx < 320; idx += 256) {
    float2 g = Gg[(size_t)bf * 320 + idx];
    *(float2*)&gl[idx * 2] = g;
  }
  const float4* ybase4 = (const float4*)(Yg + (size_t)bf * TT * 16);
  for (int fi = tid; fi < TT * 4; fi += 256) {
    const int row = fi >> 2, wq = fi & 3;
    *((float4*)&yl[row * ROWQ + wq * 4]) = ybase4[fi];
  }
  __syncthreads();

  const int t0 = tid;          // 0..255
  const int t1 = tid + 256;    // 256..511
  float acc[2][16];
  {
    const float* yr0 = &yl[t0 * ROWQ];
    const float* yr1 = &yl[t1 * ROWQ];
#pragma unroll
    for (int q = 0; q < 16; ++q) { acc[0][q] = yr0[q]; acc[1][q] = yr1[q]; }
  }
#pragma unroll 1
  for (int p = 0; p < TAPS; ++p) {
    const int rp0 = t0 - DELAY - p;        // may be <0 for tid<8
    const int rp1 = t1 - DELAY - p;        // always >=0
    const float* yrow0 = &yl[(rp0 >= 0 ? rp0 : 0) * ROWQ];
    const float* yrow1 = &yl[rp1 * ROWQ];
    const float m0 = (rp0 >= 0) ? 1.0f : 0.0f;
    const float* gp = &gl[p * 128];
#pragma unroll
    for (int d = 0; d < CHN; ++d) {
      const float y0r = m0 * yrow0[2 * d], y0i = m0 * yrow0[2 * d + 1];
      const float y1r = yrow1[2 * d],      y1i = yrow1[2 * d + 1];
      const float4 g0 = *(const float4*)&gp[d * 16 + 0];   // e0,e1
      const float4 g1 = *(const float4*)&gp[d * 16 + 4];   // e2,e3
      const float4 g2 = *(const float4*)&gp[d * 16 + 8];   // e4,e5
      const float4 g3 = *(const float4*)&gp[d * 16 + 12];  // e6,e7
      const float gr[8] = {g0.x, g0.z, g1.x, g1.z, g2.x, g2.z, g3.x, g3.z};
      const float gi[8] = {g0.y, g0.w, g1.y, g1.w, g2.y, g2.w, g3.y, g3.w};
#pragma unroll
      for (int ee = 0; ee < 8; ++ee) {
        acc[0][2 * ee]     -= gr[ee] * y0r - gi[ee] * y0i;
        acc[0][2 * ee + 1] -= gr[ee] * y0i + gi[ee] * y0r;
        acc[1][2 * ee]     -= gr[ee] * y1r - gi[ee] * y1i;
        acc[1][2 * ee + 1] -= gr[ee] * y1i + gi[ee] * y1r;
      }
    }
  }
  float* ybase = Yg + (size_t)bf * TT * 16;
  if (MODE == 0) {
#pragma unroll
    for (int s = 0; s < 2; ++s) {
      const int t = tid + s * 256;
      float ss = 0.f;
#pragma unroll
      for (int q = 0; q < 16; ++q) ss += acc[s][q] * acc[s][q];
      pw[(size_t)bf * TT + t] = ss * (1.0f / CHN);
    }
  } else {
#pragma unroll
    for (int s = 0; s < 2; ++s) {
      const int t = tid + s * 256;
      float4* dst = (float4*)(ybase + (size_t)t * 16);
      dst[0] = make_float4(acc[s][0], acc[s][1], acc[s][2], acc[s][3]);
      dst[1] = make_float4(acc[s][4], acc[s][5], acc[s][6], acc[s][7]);
      dst[2] = make_float4(acc[s][8], acc[s][9], acc[s][10], acc[s][11]);
      dst[3] = make_float4(acc[s][12], acc[s][13], acc[s][14], acc[s][15]);
    }
  }
}

// ---------------------------------------------------------------------------
// K6: Yg[b][f][t][c][2] -> out[b][t][c][f][2]
// ---------------------------------------------------------------------------
__global__ void k_unpack(const float* __restrict__ Yg, float* __restrict__ out) {
  const int ft = blockIdx.x, tt = blockIdx.y, b = blockIdx.z;
  const int f0 = ft * 32, t0 = tt * 16;
  __shared__ float ls[32 * 258];
  const int tid = threadIdx.x;
  for (int ff = 0; ff < 32; ++ff) {
    const int fg = f0 + ff;
    if (fg >= FF) break;
    ls[ff * 258 + tid] = Yg[(((size_t)b * FF + fg) * TT + t0) * 16 + tid];
  }
  __syncthreads();
  const int l = tid & 31, r = tid >> 5;
  const int fg = f0 + l;
  if (fg < FF) {
    for (int k = 0; k < 16; ++k) {
      const int task = r + 8 * k;          // 0..127 -> (t,c)
      const int t = task >> 3, c = task & 7;
      const float2 v = *(float2*)&ls[l * 258 + t * 16 + c * 2];
      *(float2*)&out[((((size_t)b * TT + t0 + t) * CHN + c) * FF + fg) * 2] = v;
    }
  }
}

// ---------------------------------------------------------------------------
extern "C" void kernel_launch(void* const* d_in, const int* in_sizes, int n_in,
                              void* d_out, int out_size, void* d_ws, size_t ws_size,
                              hipStream_t stream) {
  const float* re = (const float*)d_in[0];
  const float* im = (const float*)d_in[1];
  float* ws = (float*)d_ws;

  float*  Yg = ws;                                        // NBF*T*16 floats  (67.4 MB)
  float*  pw = Yg + (size_t)NBF * TT * 16;                // NBF*T            (4.2 MB)
  float2* Mg = (float2*)(pw + (size_t)NBF * TT);          // NBF*40*48 cplx   (31.6 MB)
  float2* Gg = Mg + (size_t)NBF * 40 * MC;                // NBF*320 cplx     (5.3 MB)
  float*  out = (float*)d_out;

  const dim3 gridT(9, 32, BB);
  k_pack<<<gridT, 256, 0, stream>>>(re, im, Yg);

  {
    const int n = NBF * TT;
    k_power0<<<(n + 255) / 256, 256, 0, stream>>>(Yg, pw);
  }

  for (int iter = 0; iter < 2; ++iter) {
    k_corr<<<NBF, 256, 0, stream>>>(Yg, pw, Mg);
    k_solve<<<NBF, 64, 0, stream>>>(Mg, Gg);
    if (iter == 0)
      k_tail<0><<<NBF, 256, 0, stream>>>(Yg, Gg, pw);   // -> power for iter 2
    else
      k_tail<1><<<NBF, 256, 0, stream>>>(Yg, Gg, pw);   // -> E in place
  }

  k_unpack<<<gridT, 256, 0, stream>>>(Yg, out);
}

// Round 5
// 827.714 us; speedup vs baseline: 6.0186x; 1.4803x over previous
//
#include <hip/hip_runtime.h>

// Problem constants (B,T,C,F fixed by harness)
constexpr int BB = 8;
constexpr int TT = 512;
constexpr int CHN = 8;
constexpr int FF = 257;
constexpr int TAPS = 5;
constexpr int DELAY = 3;
constexpr int NBF = BB * FF;          // 2056 independent (b,f) systems
constexpr int ROWQ = 20;              // k_tail LDS floats per t-row
constexpr int MC = 48;                // augmented matrix cols (40 R + 8 rhs)
constexpr int RS = 98;                // solver LDS row stride in floats (48*2 + 2 pad)

typedef float v2f __attribute__((ext_vector_type(2)));
#define FMA2(a, b, c) __builtin_elementwise_fma((a), (b), (c))

// ---------------------------------------------------------------------------
// K1: (B,T,C,F) re/im -> Yg[b][f][t][c][2]  (time-contiguous complex layout)
// ---------------------------------------------------------------------------
__global__ void k_pack(const float* __restrict__ re, const float* __restrict__ im,
                       float* __restrict__ Yg) {
  const int ft = blockIdx.x, tt = blockIdx.y, b = blockIdx.z;
  const int f0 = ft * 32, t0 = tt * 16;
  __shared__ float ls[32 * 258];
  const int tid = threadIdx.x;
  const int l = tid & 31;   // f lane
  const int r = tid >> 5;   // 0..7
  const int f = f0 + l;
  if (f < FF) {
    for (int k = 0; k < 32; ++k) {
      const int task = r + 8 * k;       // 0..255 -> (t,c,ri)
      const int ri = task & 1;
      const int c  = (task >> 1) & 7;
      const int t  = task >> 4;         // 0..15
      const float* src = ri ? im : re;
      const float v = src[(((size_t)b * TT + t0 + t) * CHN + c) * FF + f];
      ls[l * 258 + (t * 16 + c * 2 + ri)] = v;
    }
  }
  __syncthreads();
  for (int ff = 0; ff < 32; ++ff) {
    const int fg = f0 + ff;
    if (fg >= FF) break;
    Yg[(((size_t)b * FF + fg) * TT + t0) * 16 + tid] = ls[ff * 258 + tid];
  }
}

// ---------------------------------------------------------------------------
// K2: initial power[b][f][t] = mean_c |Y|^2
// ---------------------------------------------------------------------------
__global__ void k_power0(const float* __restrict__ Yg, float* __restrict__ pw) {
  const size_t idx = (size_t)blockIdx.x * blockDim.x + threadIdx.x;
  if (idx >= (size_t)NBF * TT) return;
  const float4* y4 = (const float4*)(Yg + idx * 16);
  float s = 0.f;
#pragma unroll
  for (int k = 0; k < 4; ++k) {
    float4 v = y4[k];
    s += v.x * v.x + v.y * v.y + v.z * v.z + v.w * v.w;
  }
  pw[idx] = s * (1.0f / CHN);
}

// ---------------------------------------------------------------------------
// K3: per (b,f) accumulate M = [R | b] (40x48 complex).
//   M[i=(p,d)][j] = sum_{t>=7} w[t] * conj(Y[d,t-3-p]) * z_j[t]
//   z_j = Y[e,t-3-q] for j=(q,e)<40, z_j = Y[e,t] for j=40+e.
// 4 waves per block (one block per (b,f)); each wave accumulates a 128-t
// quarter over the full 512-t panel staged planar (re|im) in LDS; partials
// reduced via 2-round LDS tree. 60 active lanes own an 8x4 complex tile,
// stored as v2f (re,im) pairs updated with packed-f32 FMAs:
//   acc += (xr,xr)*zA + (xi,xi)*zB,  zA=(w*zr, w*zi), zB=(w*zi, -w*zr)
// amdgpu_waves_per_eu(4,4): LDS caps at 4 waves/EU anyway; pin the register
// budget to 128 so acc pairs live in arch VGPRs.
// ---------------------------------------------------------------------------
__global__ __launch_bounds__(256)
__attribute__((amdgpu_waves_per_eu(4, 4)))
void k_corr(const float* __restrict__ Yg,
            const float* __restrict__ pw,
            float2* __restrict__ Mg) {
  const int bf = blockIdx.x;
  __shared__ float lds[8192 + 512];          // re[4096] | im[4096] | wl[512]
  float* pre = lds;
  float* pim = lds + 4096;
  float* wl  = lds + 8192;
  const int tid = threadIdx.x;
  const int wave = tid >> 6, lane = tid & 63;

  for (int t = tid; t < TT; t += 256) {
    const float p = pw[(size_t)bf * TT + t];
    wl[t] = (t >= DELAY + TAPS - 1) ? (1.0f / fmaxf(p, 1e-10f)) : 0.0f;
  }
  // stage interleaved global panel -> planar LDS panels
  const float4* ybase4 = (const float4*)(Yg + (size_t)bf * TT * 16);
  for (int fi = tid; fi < TT * 4; fi += 256) {
    const int t = fi >> 2, q = fi & 3;       // q = complex pair index
    const float4 v = ybase4[fi];
    *(float2*)&pre[t * 8 + 2 * q] = make_float2(v.x, v.z);
    *(float2*)&pim[t * 8 + 2 * q] = make_float2(v.y, v.w);
  }
  __syncthreads();

  const bool active = lane < 60;
  const int it = lane / 12;                 // 0..4  (p of x-block)
  const int jt = lane - it * 12;            // 0..11 (4-col z-block)
  const int xoff = DELAY + it;              // x row = t - xoff
  const int zoff = (jt < 10) ? (DELAY + (jt >> 1)) : 0;
  const int ze0  = (jt < 10) ? ((jt & 1) * 4) : ((jt - 10) * 4);

  v2f acc2[8][4];
#pragma unroll
  for (int l = 0; l < 8; ++l)
#pragma unroll
    for (int m = 0; m < 4; ++m) acc2[l][m] = (v2f){0.f, 0.f};

  const int t_lo = (wave == 0) ? (DELAY + TAPS - 1) : wave * 128;
  const int t_hi = (wave + 1) * 128;
  if (active) {
    const float* xre = &pre[(t_lo - xoff) * 8];
    const float* xim = &pim[(t_lo - xoff) * 8];
    const float* zre = &pre[(t_lo - zoff) * 8 + ze0];
    const float* zim = &pim[(t_lo - zoff) * 8 + ze0];
    for (int t = t_lo; t < t_hi; ++t) {
      const float w = wl[t];
      const float nw = -w;
      const float4 zr = *(const float4*)zre;
      const float4 zi = *(const float4*)zim;
      v2f zA[4], zB[4];
      zA[0] = (v2f){w * zr.x, w * zi.x};  zB[0] = (v2f){w * zi.x, nw * zr.x};
      zA[1] = (v2f){w * zr.y, w * zi.y};  zB[1] = (v2f){w * zi.y, nw * zr.y};
      zA[2] = (v2f){w * zr.z, w * zi.z};  zB[2] = (v2f){w * zi.z, nw * zr.z};
      zA[3] = (v2f){w * zr.w, w * zi.w};  zB[3] = (v2f){w * zi.w, nw * zr.w};
      const float4 xr0 = *(const float4*)xre;
      const float4 xr1 = *(const float4*)(xre + 4);
      const float4 xi0 = *(const float4*)xim;
      const float4 xi1 = *(const float4*)(xim + 4);
      const float xrA[8] = {xr0.x, xr0.y, xr0.z, xr0.w, xr1.x, xr1.y, xr1.z, xr1.w};
      const float xiA[8] = {xi0.x, xi0.y, xi0.z, xi0.w, xi1.x, xi1.y, xi1.z, xi1.w};
#pragma unroll
      for (int l = 0; l < 8; ++l) {
        const v2f xr2 = (v2f){xrA[l], xrA[l]};
        const v2f xi2 = (v2f){xiA[l], xiA[l]};
#pragma unroll
        for (int m = 0; m < 4; ++m) {
          acc2[l][m] = FMA2(xi2, zB[m], FMA2(xr2, zA[m], acc2[l][m]));
        }
      }
      xre += 8; xim += 8; zre += 8; zim += 8;
    }
  }

  // ---- reduce 4 wave-partials (reuse panel LDS; stride 66 floats/lane) ----
  __syncthreads();
  if ((wave == 1 || wave == 3) && active) {
    float2* dst = (float2*)(lds + (wave >> 1) * 3960 + lane * 66);
#pragma unroll
    for (int l = 0; l < 8; ++l)
#pragma unroll
      for (int m = 0; m < 4; ++m)
        dst[l * 4 + m] = make_float2(acc2[l][m].x, acc2[l][m].y);
  }
  __syncthreads();
  if ((wave == 0 || wave == 2) && active) {
    const float2* src = (const float2*)(lds + (wave >> 1) * 3960 + lane * 66);
#pragma unroll
    for (int l = 0; l < 8; ++l)
#pragma unroll
      for (int m = 0; m < 4; ++m) {
        const float2 v = src[l * 4 + m];
        acc2[l][m].x += v.x; acc2[l][m].y += v.y;
      }
  }
  __syncthreads();
  if (wave == 2 && active) {
    float2* dst = (float2*)(lds + lane * 66);
#pragma unroll
    for (int l = 0; l < 8; ++l)
#pragma unroll
      for (int m = 0; m < 4; ++m)
        dst[l * 4 + m] = make_float2(acc2[l][m].x, acc2[l][m].y);
  }
  __syncthreads();
  if (wave == 0 && active) {
    const float2* src = (const float2*)(lds + lane * 66);
#pragma unroll
    for (int l = 0; l < 8; ++l) {
      const int i = it * 8 + l;
#pragma unroll
      for (int m = 0; m < 4; ++m) {
        const int j = jt * 4 + m;
        const float2 v = src[l * 4 + m];
        float rr = acc2[l][m].x + v.x;
        if (i == j) rr += 1e-10f;           // + eps * I on the R diagonal
        Mg[((size_t)bf * 40 + i) * MC + j] = make_float2(rr, acc2[l][m].y + v.y);
      }
    }
  }
}

// ---------------------------------------------------------------------------
// K4: per (b,f) solve (R+eps I) G = b via unpivoted elimination (R is HPD).
// One wave per system, in LDS.
// ---------------------------------------------------------------------------
__global__ __launch_bounds__(64) void k_solve(const float2* __restrict__ Mg,
                                              float2* __restrict__ Gg) {
  const int bf = blockIdx.x;
  __shared__ float ml[40 * RS];
  const int lane = threadIdx.x;
  for (int idx = lane; idx < 40 * MC; idx += 64) {
    const int i = idx / MC, j = idx - i * MC;
    float2 v = Mg[((size_t)bf * 40 + i) * MC + j];
    *(float2*)&ml[i * RS + j * 2] = v;
  }
  __syncthreads();
  const int li = lane >> 3, lj = lane & 7;
  // forward elimination
  for (int k = 0; k < 40; ++k) {
    const float2 pv = *(float2*)&ml[k * RS + k * 2];
    const float den = pv.x * pv.x + pv.y * pv.y;
    const float inr = pv.x / den, ini = -pv.y / den;
    for (int i = k + 1 + li; i < 40; i += 8) {
      const float2 aik = *(float2*)&ml[i * RS + k * 2];
      const float fr = aik.x * inr - aik.y * ini;
      const float fi = aik.x * ini + aik.y * inr;
      for (int j = k + 1 + lj; j < MC; j += 8) {
        const float2 ak = *(float2*)&ml[k * RS + j * 2];
        float2 ai = *(float2*)&ml[i * RS + j * 2];
        ai.x -= fr * ak.x - fi * ak.y;
        ai.y -= fr * ak.y + fi * ak.x;
        *(float2*)&ml[i * RS + j * 2] = ai;
      }
    }
    __syncthreads();
  }
  // back substitution: lanes (cc = lane>>3 partial-chunks) x (e = lane&7 rhs)
  const int e = lane & 7, cc = lane >> 3;
  for (int k = 39; k >= 0; --k) {
    float sr = 0.f, si = 0.f;
    for (int j = k + 1 + cc; j < 40; j += 8) {
      const float2 u = *(float2*)&ml[k * RS + j * 2];
      const float2 x = *(float2*)&ml[j * RS + (40 + e) * 2];
      sr += u.x * x.x - u.y * x.y;
      si += u.x * x.y + u.y * x.x;
    }
    sr += __shfl_xor(sr, 8);  si += __shfl_xor(si, 8);
    sr += __shfl_xor(sr, 16); si += __shfl_xor(si, 16);
    sr += __shfl_xor(sr, 32); si += __shfl_xor(si, 32);
    if (cc == 0) {
      const float2 pvt = *(float2*)&ml[k * RS + k * 2];
      const float den = pvt.x * pvt.x + pvt.y * pvt.y;
      const float inr = pvt.x / den, ini = -pvt.y / den;
      const float2 rhs = *(float2*)&ml[k * RS + (40 + e) * 2];
      const float nr = rhs.x - sr, ni = rhs.y - si;
      *(float2*)&ml[k * RS + (40 + e) * 2] =
          make_float2(nr * inr - ni * ini, nr * ini + ni * inr);
    }
    __syncthreads();
  }
  for (int idx = lane; idx < 320; idx += 64) {
    const int i = idx >> 3, ee = idx & 7;
    Gg[(size_t)bf * 320 + idx] = *(float2*)&ml[i * RS + (40 + ee) * 2];
  }
}

// ---------------------------------------------------------------------------
// K5: E[e,t] = Y[e,t] - sum_{p,d} G[p,d,e] * Y[d,t-3-p]
// 256 threads/block, one block per (b,f). Whole 512-frame panel staged in LDS.
// MODE 0: write power = mean_e |E|^2 (for iteration 2), discard E.
// MODE 1: overwrite Yg with E in place.
// ---------------------------------------------------------------------------
template <int MODE>
__global__ __launch_bounds__(256) void k_tail(float* __restrict__ Yg,
                                              const float2* __restrict__ Gg,
                                              float* __restrict__ pw) {
  const int bf = blockIdx.x;
  __shared__ float yl[TT * ROWQ];     // 40960 B
  __shared__ float gl[640];           // 2560 B: gl[((p*8+d)*8+e)*2 + ri]
  const int tid = threadIdx.x;
  for (int idx = tid; idx < 320; idx += 256) {
    float2 g = Gg[(size_t)bf * 320 + idx];
    *(float2*)&gl[idx * 2] = g;
  }
  const float4* ybase4 = (const float4*)(Yg + (size_t)bf * TT * 16);
  for (int fi = tid; fi < TT * 4; fi += 256) {
    const int row = fi >> 2, wq = fi & 3;
    *((float4*)&yl[row * ROWQ + wq * 4]) = ybase4[fi];
  }
  __syncthreads();

  const int t0 = tid;          // 0..255
  const int t1 = tid + 256;    // 256..511
  float acc[2][16];
  {
    const float* yr0 = &yl[t0 * ROWQ];
    const float* yr1 = &yl[t1 * ROWQ];
#pragma unroll
    for (int q = 0; q < 16; ++q) { acc[0][q] = yr0[q]; acc[1][q] = yr1[q]; }
  }
#pragma unroll 1
  for (int p = 0; p < TAPS; ++p) {
    const int rp0 = t0 - DELAY - p;        // may be <0 for tid<8
    const int rp1 = t1 - DELAY - p;        // always >=0
    const float* yrow0 = &yl[(rp0 >= 0 ? rp0 : 0) * ROWQ];
    const float* yrow1 = &yl[rp1 * ROWQ];
    const float m0 = (rp0 >= 0) ? 1.0f : 0.0f;
    const float* gp = &gl[p * 128];
#pragma unroll
    for (int d = 0; d < CHN; ++d) {
      const float y0r = m0 * yrow0[2 * d], y0i = m0 * yrow0[2 * d + 1];
      const float y1r = yrow1[2 * d],      y1i = yrow1[2 * d + 1];
      const float4 g0 = *(const float4*)&gp[d * 16 + 0];   // e0,e1
      const float4 g1 = *(const float4*)&gp[d * 16 + 4];   // e2,e3
      const float4 g2 = *(const float4*)&gp[d * 16 + 8];   // e4,e5
      const float4 g3 = *(const float4*)&gp[d * 16 + 12];  // e6,e7
      const float gr[8] = {g0.x, g0.z, g1.x, g1.z, g2.x, g2.z, g3.x, g3.z};
      const float gi[8] = {g0.y, g0.w, g1.y, g1.w, g2.y, g2.w, g3.y, g3.w};
#pragma unroll
      for (int ee = 0; ee < 8; ++ee) {
        acc[0][2 * ee]     -= gr[ee] * y0r - gi[ee] * y0i;
        acc[0][2 * ee + 1] -= gr[ee] * y0i + gi[ee] * y0r;
        acc[1][2 * ee]     -= gr[ee] * y1r - gi[ee] * y1i;
        acc[1][2 * ee + 1] -= gr[ee] * y1i + gi[ee] * y1r;
      }
    }
  }
  float* ybase = Yg + (size_t)bf * TT * 16;
  if (MODE == 0) {
#pragma unroll
    for (int s = 0; s < 2; ++s) {
      const int t = tid + s * 256;
      float ss = 0.f;
#pragma unroll
      for (int q = 0; q < 16; ++q) ss += acc[s][q] * acc[s][q];
      pw[(size_t)bf * TT + t] = ss * (1.0f / CHN);
    }
  } else {
#pragma unroll
    for (int s = 0; s < 2; ++s) {
      const int t = tid + s * 256;
      float4* dst = (float4*)(ybase + (size_t)t * 16);
      dst[0] = make_float4(acc[s][0], acc[s][1], acc[s][2], acc[s][3]);
      dst[1] = make_float4(acc[s][4], acc[s][5], acc[s][6], acc[s][7]);
      dst[2] = make_float4(acc[s][8], acc[s][9], acc[s][10], acc[s][11]);
      dst[3] = make_float4(acc[s][12], acc[s][13], acc[s][14], acc[s][15]);
    }
  }
}

// ---------------------------------------------------------------------------
// K6: Yg[b][f][t][c][2] -> out[b][t][c][f][2]
// ---------------------------------------------------------------------------
__global__ void k_unpack(const float* __restrict__ Yg, float* __restrict__ out) {
  const int ft = blockIdx.x, tt = blockIdx.y, b = blockIdx.z;
  const int f0 = ft * 32, t0 = tt * 16;
  __shared__ float ls[32 * 258];
  const int tid = threadIdx.x;
  for (int ff = 0; ff < 32; ++ff) {
    const int fg = f0 + ff;
    if (fg >= FF) break;
    ls[ff * 258 + tid] = Yg[(((size_t)b * FF + fg) * TT + t0) * 16 + tid];
  }
  __syncthreads();
  const int l = tid & 31, r = tid >> 5;
  const int fg = f0 + l;
  if (fg < FF) {
    for (int k = 0; k < 16; ++k) {
      const int task = r + 8 * k;          // 0..127 -> (t,c)
      const int t = task >> 3, c = task & 7;
      const float2 v = *(float2*)&ls[l * 258 + t * 16 + c * 2];
      *(float2*)&out[((((size_t)b * TT + t0 + t) * CHN + c) * FF + fg) * 2] = v;
    }
  }
}

// ---------------------------------------------------------------------------
extern "C" void kernel_launch(void* const* d_in, const int* in_sizes, int n_in,
                              void* d_out, int out_size, void* d_ws, size_t ws_size,
                              hipStream_t stream) {
  const float* re = (const float*)d_in[0];
  const float* im = (const float*)d_in[1];
  float* ws = (float*)d_ws;

  float*  Yg = ws;                                        // NBF*T*16 floats  (67.4 MB)
  float*  pw = Yg + (size_t)NBF * TT * 16;                // NBF*T            (4.2 MB)
  float2* Mg = (float2*)(pw + (size_t)NBF * TT);          // NBF*40*48 cplx   (31.6 MB)
  float2* Gg = Mg + (size_t)NBF * 40 * MC;                // NBF*320 cplx     (5.3 MB)
  float*  out = (float*)d_out;

  const dim3 gridT(9, 32, BB);
  k_pack<<<gridT, 256, 0, stream>>>(re, im, Yg);

  {
    const int n = NBF * TT;
    k_power0<<<(n + 255) / 256, 256, 0, stream>>>(Yg, pw);
  }

  for (int iter = 0; iter < 2; ++iter) {
    k_corr<<<NBF, 256, 0, stream>>>(Yg, pw, Mg);
    k_solve<<<NBF, 64, 0, stream>>>(Mg, Gg);
    if (iter == 0)
      k_tail<0><<<NBF, 256, 0, stream>>>(Yg, Gg, pw);   // -> power for iter 2
    else
      k_tail<1><<<NBF, 256, 0, stream>>>(Yg, Gg, pw);   // -> E in place
  }

  k_unpack<<<gridT, 256, 0, stream>>>(Yg, out);
}